// Round 5
// baseline (241.255 us; speedup 1.0000x reference)
//
#include <hip/hip_runtime.h>
#include <math.h>

#define NBINS 15

typedef float f32x4 __attribute__((ext_vector_type(4)));

// ws layout (floats): [0..14] counts, [16..30] sum_conf, [32..46] sum_acc,
//                     [48] done-counter (as uint bits)
__global__ void ece_init(float* accum) {
    int t = threadIdx.x;
    if (t < 64) accum[t] = 0.0f;
}

__global__ __launch_bounds__(256) void ece_main(
    const float* __restrict__ logits,
    const int* __restrict__ labels,
    const float* __restrict__ temp,
    float* __restrict__ accum,
    int N, float nTotal)
{
    const float k = (1.0f / temp[0]) * 1.44269504088896340736f;  // invT*log2(e)
    const int tid  = threadIdx.x;
    const int lane = tid & 63;
    const int c    = lane & 15;   // position within 16-lane row group
    const int g    = lane >> 4;   // which of the wave's 4 rows in a group
    const int wavesPerBlock = blockDim.x >> 6;
    const long long waveId     = (long long)blockIdx.x * wavesPerBlock + (tid >> 6);
    const long long totalWaves = (long long)gridDim.x * wavesPerBlock;

    const f32x4* logits4 = reinterpret_cast<const f32x4*>(logits);
    float cnt = 0.f, sconf = 0.f, sacc = 0.f;
    const bool has2 = (c < 9);  // 100 floats = 16 f32x4 + 9 f32x4

    // 16 rows per wave-iteration; all 8 vector loads + 4 label loads hoisted
    for (long long base = waveId * 16; base < (long long)N; base += totalWaves * 16) {
        f32x4 a[4], b[4];
        int   lbl[4];
        bool  valid[4];
#pragma unroll
        for (int j = 0; j < 4; j++) {
            long long row = base + 4 * j + g;
            valid[j] = (row < (long long)N);
            long long r = valid[j] ? row : (long long)(N - 1);
            const f32x4* rowp4 = logits4 + (size_t)r * 25;
            a[j] = rowp4[c];
            b[j] = has2 ? rowp4[16 + c]
                        : (f32x4){-INFINITY, -INFINITY, -INFINITY, -INFINITY};
            lbl[j] = labels[r];
        }
#pragma unroll
        for (int j = 0; j < 4; j++) {
            f32x4 av = a[j] * k;
            f32x4 bv = b[j] * k;

            // local first-argmax (strict > keeps lowest index on ties)
            float lm = av.x; int lidx = 4 * c;
            if (av.y > lm) { lm = av.y; lidx = 4 * c + 1; }
            if (av.z > lm) { lm = av.z; lidx = 4 * c + 2; }
            if (av.w > lm) { lm = av.w; lidx = 4 * c + 3; }
            if (bv.x > lm) { lm = bv.x; lidx = 64 + 4 * c; }
            if (bv.y > lm) { lm = bv.y; lidx = 64 + 4 * c + 1; }
            if (bv.z > lm) { lm = bv.z; lidx = 64 + 4 * c + 2; }
            if (bv.w > lm) { lm = bv.w; lidx = 64 + 4 * c + 3; }

            // local exp2-sum vs LOCAL max (off the reduce critical path);
            // exp2(-INF - lm) = 0 handles the !has2 lanes.
            float s0 = __builtin_amdgcn_exp2f(av.x - lm) + __builtin_amdgcn_exp2f(av.y - lm)
                     + __builtin_amdgcn_exp2f(av.z - lm) + __builtin_amdgcn_exp2f(av.w - lm)
                     + __builtin_amdgcn_exp2f(bv.x - lm) + __builtin_amdgcn_exp2f(bv.y - lm)
                     + __builtin_amdgcn_exp2f(bv.z - lm) + __builtin_amdgcn_exp2f(bv.w - lm);

            // 16-lane all-reduce max
            float gm = lm;
            gm = fmaxf(gm, __shfl_xor(gm, 1));
            gm = fmaxf(gm, __shfl_xor(gm, 2));
            gm = fmaxf(gm, __shfl_xor(gm, 4));
            gm = fmaxf(gm, __shfl_xor(gm, 8));

            // first global index achieving gm
            int cand = (lm == gm) ? lidx : 0x7fffffff;
            cand = min(cand, __shfl_xor(cand, 1));
            cand = min(cand, __shfl_xor(cand, 2));
            cand = min(cand, __shfl_xor(cand, 4));
            cand = min(cand, __shfl_xor(cand, 8));

            // rebase local sum to global max, then sum-reduce
            float s = s0 * __builtin_amdgcn_exp2f(lm - gm);
            s += __shfl_xor(s, 1);
            s += __shfl_xor(s, 2);
            s += __shfl_xor(s, 4);
            s += __shfl_xor(s, 8);

            float conf = 1.0f / s;
            float acc  = (cand == lbl[j]) ? 1.0f : 0.0f;
            int bin = (int)ceilf(conf * 15.0f) - 1;
            bin = bin < 0 ? 0 : (bin > 14 ? 14 : bin);

            if (valid[j] && c == bin) {   // lane c owns bin c
                cnt   += 1.0f;
                sconf += conf;
                sacc  += acc;
            }
        }
    }

    __shared__ float sh[48];
    if (tid < 48) sh[tid] = 0.0f;
    __syncthreads();
    if (c < NBINS) {
        atomicAdd(&sh[c],      cnt);
        atomicAdd(&sh[16 + c], sconf);
        atomicAdd(&sh[32 + c], sacc);
    }
    __syncthreads();
    if (tid < 48) {
        atomicAdd(&accum[tid], sh[tid]);   // tid<48 all in wave 0
    }

    // last block finishes the reduction (device-scope counter)
    __shared__ int amLast;
    if (tid == 0) {
        __threadfence();   // drain this wave's accum atomics to device scope
        unsigned old = atomicAdd(reinterpret_cast<unsigned*>(accum + 48), 1u);
        amLast = (old == (unsigned)(gridDim.x - 1));
    }
    __syncthreads();
    if (amLast) {
        float e = 0.0f;
        if (tid < NBINS) {
            // atomic read-modify-write of 0 → device-coherent read across XCDs
            float cv = atomicAdd(&accum[tid],      0.0f);
            float sc = atomicAdd(&accum[16 + tid], 0.0f);
            float sa = atomicAdd(&accum[32 + tid], 0.0f);
            float safe = fmaxf(cv, 1.0f);
            float gap  = (cv > 0.0f) ? fabsf(sc / safe - sa / safe) : 0.0f;
            e = gap * (cv / nTotal);
        }
        if (tid < 16) {
            e += __shfl_xor(e, 1);
            e += __shfl_xor(e, 2);
            e += __shfl_xor(e, 4);
            e += __shfl_xor(e, 8);
        }
        if (tid == 0) {
            float* out = accum + 56;       // stash, then write below
            out[0] = e;                    // (same thread writes d_out via param)
        }
    }
}

__global__ void ece_out(const float* __restrict__ accum, float* __restrict__ out) {
    if (threadIdx.x == 0) out[0] = accum[56];
}

extern "C" void kernel_launch(void* const* d_in, const int* in_sizes, int n_in,
                              void* d_out, int out_size, void* d_ws, size_t ws_size,
                              hipStream_t stream) {
    const float* logits = (const float*)d_in[0];
    const int*   labels = (const int*)d_in[1];
    const float* temp   = (const float*)d_in[2];
    float* accum = (float*)d_ws;
    const int N = in_sizes[1];   // labels count; logits is N*100

    ece_init<<<1, 64, 0, stream>>>(accum);
    ece_main<<<2048, 256, 0, stream>>>(logits, labels, temp, accum, N, (float)N);
    ece_out<<<1, 64, 0, stream>>>(accum, (float*)d_out);
}

// Round 6
// 238.298 us; speedup vs baseline: 1.0124x; 1.0124x over previous
//
#include <hip/hip_runtime.h>
#include <math.h>

#define NBINS 15

typedef float f32x4 __attribute__((ext_vector_type(4)));

// ws layout (floats): [0..14] counts, [16..30] sum_conf, [32..46] sum_acc,
//                     [48] done-counter (uint bits)
__global__ void ece_init(float* accum) {
    int t = threadIdx.x;
    if (t < 64) accum[t] = 0.0f;
}

__global__ __launch_bounds__(256, 8) void ece_main(
    const float* __restrict__ logits,
    const int* __restrict__ labels,
    const float* __restrict__ temp,
    float* __restrict__ accum,
    float* __restrict__ out,
    int N, float nTotal)
{
    const float k = (1.0f / temp[0]) * 1.44269504088896340736f;  // invT*log2(e)
    const int tid  = threadIdx.x;
    const int lane = tid & 63;
    const int c    = lane & 15;   // position within 16-lane row group
    const int g    = lane >> 4;   // which of the wave's 4 rows
    const int wavesPerBlock = blockDim.x >> 6;
    const long long waveId     = (long long)blockIdx.x * wavesPerBlock + (tid >> 6);
    const long long totalWaves = (long long)gridDim.x * wavesPerBlock;
    const long long stride     = totalWaves * 4;

    const f32x4* logits4 = reinterpret_cast<const f32x4*>(logits);
    float cnt = 0.f, sconf = 0.f, sacc = 0.f;
    const bool has2 = (c < 9);  // 100 floats = 16 f32x4 + 9 f32x4
    const f32x4 NEGINF = (f32x4){-INFINITY, -INFINITY, -INFINITY, -INFINITY};

    long long base = waveId * 4;
    if (base < (long long)N) {
        // prefetch iteration 0
        long long row0 = base + g;
        bool v_cur = (row0 < (long long)N);
        long long r0 = v_cur ? row0 : (long long)(N - 1);
        const f32x4* rp0 = logits4 + (size_t)r0 * 25;
        f32x4 a_cur = rp0[c];
        f32x4 b_cur = has2 ? rp0[16 + c] : NEGINF;
        int   l_cur = labels[r0];

        while (true) {
            long long nbase = base + stride;
            bool haveNext = (nbase < (long long)N);
            f32x4 a_nxt, b_nxt;
            int   l_nxt = 0;
            bool  v_nxt = false;
            if (haveNext) {
                long long rown = nbase + g;
                v_nxt = (rown < (long long)N);
                long long rn = v_nxt ? rown : (long long)(N - 1);
                const f32x4* rpn = logits4 + (size_t)rn * 25;
                a_nxt = rpn[c];                      // issue loads NOW,
                b_nxt = has2 ? rpn[16 + c] : NEGINF; // consumed next iter
                l_nxt = labels[rn];
            }

            // ---- compute on current (loads for next are in flight) ----
            f32x4 av = a_cur * k;
            f32x4 bv = b_cur * k;

            float lm = av.x; int lidx = 4 * c;
            if (av.y > lm) { lm = av.y; lidx = 4 * c + 1; }
            if (av.z > lm) { lm = av.z; lidx = 4 * c + 2; }
            if (av.w > lm) { lm = av.w; lidx = 4 * c + 3; }
            if (bv.x > lm) { lm = bv.x; lidx = 64 + 4 * c; }
            if (bv.y > lm) { lm = bv.y; lidx = 64 + 4 * c + 1; }
            if (bv.z > lm) { lm = bv.z; lidx = 64 + 4 * c + 2; }
            if (bv.w > lm) { lm = bv.w; lidx = 64 + 4 * c + 3; }

            float s0 = __builtin_amdgcn_exp2f(av.x - lm) + __builtin_amdgcn_exp2f(av.y - lm)
                     + __builtin_amdgcn_exp2f(av.z - lm) + __builtin_amdgcn_exp2f(av.w - lm)
                     + __builtin_amdgcn_exp2f(bv.x - lm) + __builtin_amdgcn_exp2f(bv.y - lm)
                     + __builtin_amdgcn_exp2f(bv.z - lm) + __builtin_amdgcn_exp2f(bv.w - lm);

            float gm = lm;
            gm = fmaxf(gm, __shfl_xor(gm, 1));
            gm = fmaxf(gm, __shfl_xor(gm, 2));
            gm = fmaxf(gm, __shfl_xor(gm, 4));
            gm = fmaxf(gm, __shfl_xor(gm, 8));

            int cand = (lm == gm) ? lidx : 0x7fffffff;
            cand = min(cand, __shfl_xor(cand, 1));
            cand = min(cand, __shfl_xor(cand, 2));
            cand = min(cand, __shfl_xor(cand, 4));
            cand = min(cand, __shfl_xor(cand, 8));

            float s = s0 * __builtin_amdgcn_exp2f(lm - gm);
            s += __shfl_xor(s, 1);
            s += __shfl_xor(s, 2);
            s += __shfl_xor(s, 4);
            s += __shfl_xor(s, 8);

            float conf = 1.0f / s;
            float acc  = (cand == l_cur) ? 1.0f : 0.0f;
            int bin = (int)ceilf(conf * 15.0f) - 1;
            bin = bin < 0 ? 0 : (bin > 14 ? 14 : bin);

            if (v_cur && c == bin) {   // lane c owns bin c
                cnt   += 1.0f;
                sconf += conf;
                sacc  += acc;
            }

            if (!haveNext) break;
            a_cur = a_nxt; b_cur = b_nxt; l_cur = l_nxt; v_cur = v_nxt;
            base = nbase;
        }
    }

    __shared__ float sh[48];
    if (tid < 48) sh[tid] = 0.0f;
    __syncthreads();
    if (c < NBINS) {
        atomicAdd(&sh[c],      cnt);
        atomicAdd(&sh[16 + c], sconf);
        atomicAdd(&sh[32 + c], sacc);
    }
    __syncthreads();
    if (tid < 48) {
        atomicAdd(&accum[tid], sh[tid]);
    }

    // last block computes the final ECE (device-scope done counter)
    __shared__ int amLast;
    if (tid == 0) {
        __threadfence();
        unsigned old = atomicAdd(reinterpret_cast<unsigned*>(accum + 48), 1u);
        amLast = (old == (unsigned)(gridDim.x - 1));
    }
    __syncthreads();
    if (amLast) {
        float e = 0.0f;
        if (tid < NBINS) {
            float cv = atomicAdd(&accum[tid],      0.0f);  // coherent read
            float sc = atomicAdd(&accum[16 + tid], 0.0f);
            float sa = atomicAdd(&accum[32 + tid], 0.0f);
            float safe = fmaxf(cv, 1.0f);
            float gap  = (cv > 0.0f) ? fabsf(sc / safe - sa / safe) : 0.0f;
            e = gap * (cv / nTotal);
        }
        if (tid < 16) {
            e += __shfl_xor(e, 1);
            e += __shfl_xor(e, 2);
            e += __shfl_xor(e, 4);
            e += __shfl_xor(e, 8);
            if (tid == 0) out[0] = e;
        }
    }
}

extern "C" void kernel_launch(void* const* d_in, const int* in_sizes, int n_in,
                              void* d_out, int out_size, void* d_ws, size_t ws_size,
                              hipStream_t stream) {
    const float* logits = (const float*)d_in[0];
    const int*   labels = (const int*)d_in[1];
    const float* temp   = (const float*)d_in[2];
    float* accum = (float*)d_ws;
    const int N = in_sizes[1];   // labels count; logits is N*100

    ece_init<<<1, 64, 0, stream>>>(accum);
    ece_main<<<2048, 256, 0, stream>>>(logits, labels, temp, accum,
                                       (float*)d_out, N, (float)N);
}

// Round 7
// 174.502 us; speedup vs baseline: 1.3825x; 1.3656x over previous
//
#include <hip/hip_runtime.h>
#include <math.h>

#define NBINS 15

typedef float f32x4 __attribute__((ext_vector_type(4)));

// accum layout in d_ws (48 floats): [0..14] counts, [16..30] sum_conf, [32..46] sum_acc
__global__ void ece_init(float* accum) {
    int t = threadIdx.x;
    if (t < 48) accum[t] = 0.0f;
}

// Process one 4-row group (16 lanes per row). k = invT * log2(e): work in
// exp2 domain (monotone, so argmax/ties unchanged; v_exp_f32 is 2^x).
__device__ __forceinline__ void process4(
    const f32x4* __restrict__ logits4,
    const int* __restrict__ labels,
    long long base, int g, int c, bool has2, float k, int N,
    float& cnt, float& sconf, float& sacc)
{
    long long row = base + g;
    const bool valid = (row < (long long)N);
    const long long r = valid ? row : (long long)(N - 1);
    const f32x4* rowp4 = logits4 + (size_t)r * 25;   // 100 floats = 25 float4

    f32x4 a = __builtin_nontemporal_load(rowp4 + c);
    f32x4 b = (f32x4){-INFINITY, -INFINITY, -INFINITY, -INFINITY};
    if (has2) b = __builtin_nontemporal_load(rowp4 + 16 + c);

    a *= k;
    b *= k;

    // local first-argmax (strict > keeps lowest index on ties)
    float lm = a.x; int lidx = 4 * c;
    if (a.y > lm) { lm = a.y; lidx = 4 * c + 1; }
    if (a.z > lm) { lm = a.z; lidx = 4 * c + 2; }
    if (a.w > lm) { lm = a.w; lidx = 4 * c + 3; }
    if (b.x > lm) { lm = b.x; lidx = 64 + 4 * c; }
    if (b.y > lm) { lm = b.y; lidx = 64 + 4 * c + 1; }
    if (b.z > lm) { lm = b.z; lidx = 64 + 4 * c + 2; }
    if (b.w > lm) { lm = b.w; lidx = 64 + 4 * c + 3; }

    // local exp2-sum vs LOCAL max — off the reduce critical path.
    // exp2(-INF - lm) = 0, so the !has2 lanes contribute 0 from b.
    float s0 = __builtin_amdgcn_exp2f(a.x - lm) + __builtin_amdgcn_exp2f(a.y - lm)
             + __builtin_amdgcn_exp2f(a.z - lm) + __builtin_amdgcn_exp2f(a.w - lm)
             + __builtin_amdgcn_exp2f(b.x - lm) + __builtin_amdgcn_exp2f(b.y - lm)
             + __builtin_amdgcn_exp2f(b.z - lm) + __builtin_amdgcn_exp2f(b.w - lm);

    // 16-lane all-reduce max
    float gm = lm;
    gm = fmaxf(gm, __shfl_xor(gm, 1));
    gm = fmaxf(gm, __shfl_xor(gm, 2));
    gm = fmaxf(gm, __shfl_xor(gm, 4));
    gm = fmaxf(gm, __shfl_xor(gm, 8));

    // first global index achieving gm
    int cand = (lm == gm) ? lidx : 0x7fffffff;
    cand = min(cand, __shfl_xor(cand, 1));
    cand = min(cand, __shfl_xor(cand, 2));
    cand = min(cand, __shfl_xor(cand, 4));
    cand = min(cand, __shfl_xor(cand, 8));

    // rebase local sum to global max, then sum-reduce
    float s = s0 * __builtin_amdgcn_exp2f(lm - gm);
    s += __shfl_xor(s, 1);
    s += __shfl_xor(s, 2);
    s += __shfl_xor(s, 4);
    s += __shfl_xor(s, 8);

    float conf = 1.0f / s;
    int   lbl  = labels[r];
    float acc  = (cand == lbl) ? 1.0f : 0.0f;
    int bin = (int)ceilf(conf * 15.0f) - 1;
    bin = bin < 0 ? 0 : (bin > 14 ? 14 : bin);

    if (valid && c == bin) {   // lane c owns bin c
        cnt   += 1.0f;
        sconf += conf;
        sacc  += acc;
    }
}

__global__ __launch_bounds__(256, 8) void ece_main(
    const float* __restrict__ logits,
    const int* __restrict__ labels,
    const float* __restrict__ temp,
    float* __restrict__ accum,
    int N)
{
    const float k = (1.0f / temp[0]) * 1.44269504088896340736f;  // invT * log2(e)
    const int tid  = threadIdx.x;
    const int lane = tid & 63;
    const int c    = lane & 15;
    const int g    = lane >> 4;
    const int wavesPerBlock = blockDim.x >> 6;
    const long long waveId     = (long long)blockIdx.x * wavesPerBlock + (tid >> 6);
    const long long totalWaves = (long long)gridDim.x * wavesPerBlock;

    const f32x4* logits4 = reinterpret_cast<const f32x4*>(logits);
    float cnt = 0.f, sconf = 0.f, sacc = 0.f;
    const bool has2 = (c < 9);  // 100 floats = 16 f32x4 + 9 f32x4

    // 8 rows per wave-iteration: two independent 4-row chains for ILP
    for (long long base = waveId * 8; base < (long long)N; base += totalWaves * 8) {
        process4(logits4, labels, base,     g, c, has2, k, N, cnt, sconf, sacc);
        process4(logits4, labels, base + 4, g, c, has2, k, N, cnt, sconf, sacc);
    }

    __shared__ float sh[48];
    if (tid < 48) sh[tid] = 0.0f;
    __syncthreads();
    if (c < NBINS) {
        atomicAdd(&sh[c],      cnt);
        atomicAdd(&sh[16 + c], sconf);
        atomicAdd(&sh[32 + c], sacc);
    }
    __syncthreads();
    if (tid < 48) {
        atomicAdd(&accum[tid], sh[tid]);
    }
}

__global__ void ece_final(const float* __restrict__ accum, float* __restrict__ out, float nTotal) {
    if (threadIdx.x == 0) {
        float e = 0.0f;
        for (int b = 0; b < NBINS; b++) {
            float cntv = accum[b];
            float sc   = accum[16 + b];
            float sa   = accum[32 + b];
            float safe = fmaxf(cntv, 1.0f);
            float gap  = (cntv > 0.0f) ? fabsf(sc / safe - sa / safe) : 0.0f;
            e += gap * (cntv / nTotal);
        }
        out[0] = e;
    }
}

extern "C" void kernel_launch(void* const* d_in, const int* in_sizes, int n_in,
                              void* d_out, int out_size, void* d_ws, size_t ws_size,
                              hipStream_t stream) {
    const float* logits = (const float*)d_in[0];
    const int*   labels = (const int*)d_in[1];
    const float* temp   = (const float*)d_in[2];
    float* accum = (float*)d_ws;
    const int N = in_sizes[1];   // labels count; logits is N*100

    ece_init<<<1, 64, 0, stream>>>(accum);
    ece_main<<<2048, 256, 0, stream>>>(logits, labels, temp, accum, N);
    ece_final<<<1, 64, 0, stream>>>(accum, (float*)d_out, (float)N);
}